// Round 12
// baseline (979.745 us; speedup 1.0000x reference)
//
#include <hip/hip_runtime.h>

#define N_    64
#define W_    512
#define H_    512
#define S_    513
#define TWOH_ 1024
#define KS_   8
#define FIXCAP_ 131072

typedef short s16x8 __attribute__((ext_vector_type(8)));
typedef float f32x4 __attribute__((ext_vector_type(4)));
typedef _Float16 h16x8 __attribute__((ext_vector_type(8)));
typedef _Float16 h16x4 __attribute__((ext_vector_type(4)));

__device__ __forceinline__ float tanh_fast(float x) {
  float xc = fminf(fmaxf(x, -15.0f), 15.0f);
  float e = __expf(2.0f * xc);
  return (e - 1.0f) / (e + 1.0f);
}
__device__ __forceinline__ float sigmoid_f(float x) {
  return 1.0f / (1.0f + __expf(-x));
}
__device__ __forceinline__ float wred_sum(float v) {
#pragma unroll
  for (int m = 32; m > 0; m >>= 1) v += __shfl_xor(v, m, 64);
  return v;
}
__device__ __forceinline__ float bf2f(unsigned short u) {
  return __uint_as_float(((unsigned)u) << 16);
}

__device__ __forceinline__ void gld_lds16(const void* g, void* s) {
  __builtin_amdgcn_global_load_lds((__attribute__((address_space(1))) void*)g,
                                   (__attribute__((address_space(3))) void*)s,
                                   16, 0, 0);
}

// ---------------------------------------------------------------------------
// conversions in one dispatch: ctx/Vw -> split-bf16 (hi,lo); Ww -> fp16.
// ---------------------------------------------------------------------------
__global__ __launch_bounds__(256) void k_cvt2(
    const float4* __restrict__ xa, unsigned short* __restrict__ Ahi,
    unsigned short* __restrict__ Alo, const float4* __restrict__ xb,
    unsigned short* __restrict__ Bhi, unsigned short* __restrict__ Blo,
    const float4* __restrict__ xw, _Float16* __restrict__ W16) {
  const int NA = 8388608;          // ctx float4 count
  const int NB = 131072;           // Vw float4 count
  const int NW = 65536;            // Ww float4 count
  const int NT = NA + NB + NW;
  for (int i = blockIdx.x * 256 + threadIdx.x; i < NT; i += gridDim.x * 256) {
    if (i < NA + NB) {
      bool isA = (i < NA);
      float4 v = isA ? xa[i] : xb[i - NA];
      float vs[4] = {v.x, v.y, v.z, v.w};
      unsigned short hb[4], lb[4];
#pragma unroll
      for (int j = 0; j < 4; ++j) {
        unsigned u = __float_as_uint(vs[j]);
        unsigned short h = (unsigned short)((u + 0x7FFFu + ((u >> 16) & 1u)) >> 16);
        float hf = __uint_as_float((unsigned)h << 16);
        float lf = vs[j] - hf;
        unsigned u2 = __float_as_uint(lf);
        unsigned short l = (unsigned short)((u2 + 0x7FFFu + ((u2 >> 16) & 1u)) >> 16);
        hb[j] = h; lb[j] = l;
      }
      ushort4 h4; h4.x = hb[0]; h4.y = hb[1]; h4.z = hb[2]; h4.w = hb[3];
      ushort4 l4; l4.x = lb[0]; l4.y = lb[1]; l4.z = lb[2]; l4.w = lb[3];
      if (isA) {
        ((ushort4*)Ahi)[i] = h4;
        ((ushort4*)Alo)[i] = l4;
      } else {
        ((ushort4*)Bhi)[i - NA] = h4;
        ((ushort4*)Blo)[i - NA] = l4;
      }
    } else {
      int j = i - NA - NB;
      float4 v = xw[j];
      h16x4 o;
      o[0] = (_Float16)v.x; o[1] = (_Float16)v.y;
      o[2] = (_Float16)v.z; o[3] = (_Float16)v.w;
      *(h16x4*)(W16 + (size_t)4 * j) = o;
    }
  }
}

// ---------------------------------------------------------------------------
// Vc16 = (half)(A * B^T) via 3-product split-bf16 MFMA (round-7 exact).
// ---------------------------------------------------------------------------
__global__ __launch_bounds__(256, 2) void mfma_gemm(
    const unsigned short* __restrict__ Ahi, const unsigned short* __restrict__ Alo,
    const unsigned short* __restrict__ Bhi, const unsigned short* __restrict__ Blo,
    _Float16* __restrict__ C) {
  __shared__ unsigned short sAh[4096], sAl[4096], sBh[4096], sBl[4096];
  int bid = blockIdx.x;
  int swz = (bid & 7) * 128 + (bid >> 3);  // 1024 wgs, bijective, XCD-chunked
  int mt = swz >> 2, nt = swz & 3;
  int m0 = mt * 128, n0 = nt * 128;
  int tid = threadIdx.x;
  int wave = tid >> 6, lane = tid & 63;
  int wr = wave >> 1, wc = wave & 1;
  int fr = lane & 15, fq = lane >> 4;
  int rA = tid >> 2;
  int cA = (tid & 3) * 8;

  f32x4 acc[4][4] = {};

  const size_t a_row0 = (size_t)(m0 + rA) << 10;
  const size_t a_row1 = (size_t)(m0 + rA + 64) << 10;
  const size_t b_row0 = (size_t)(n0 + rA) << 10;
  const size_t b_row1 = (size_t)(n0 + rA + 64) << 10;
  const int wofs = wave << 9;

  for (int k0 = 0; k0 < 1024; k0 += 32) {
    int off = k0 + cA;
    gld_lds16(Ahi + a_row0 + off, sAh + wofs);
    gld_lds16(Ahi + a_row1 + off, sAh + 2048 + wofs);
    gld_lds16(Alo + a_row0 + off, sAl + wofs);
    gld_lds16(Alo + a_row1 + off, sAl + 2048 + wofs);
    gld_lds16(Bhi + b_row0 + off, sBh + wofs);
    gld_lds16(Bhi + b_row1 + off, sBh + 2048 + wofs);
    gld_lds16(Blo + b_row0 + off, sBl + wofs);
    gld_lds16(Blo + b_row1 + off, sBl + 2048 + wofs);
    __syncthreads();
    s16x8 ah[4], av[4], bh[4], bv[4];
#pragma unroll
    for (int m = 0; m < 4; ++m) {
      int ar = (wr * 64 + m * 16 + fr) * 32 + fq * 8;
      ah[m] = *(const s16x8*)(sAh + ar);
      av[m] = *(const s16x8*)(sAl + ar);
    }
#pragma unroll
    for (int n = 0; n < 4; ++n) {
      int br = (wc * 64 + n * 16 + fr) * 32 + fq * 8;
      bh[n] = *(const s16x8*)(sBh + br);
      bv[n] = *(const s16x8*)(sBl + br);
    }
#pragma unroll
    for (int m = 0; m < 4; ++m)
#pragma unroll
      for (int n = 0; n < 4; ++n) {
        acc[m][n] = __builtin_amdgcn_mfma_f32_16x16x32_bf16(ah[m], bh[n], acc[m][n], 0, 0, 0);
        acc[m][n] = __builtin_amdgcn_mfma_f32_16x16x32_bf16(ah[m], bv[n], acc[m][n], 0, 0, 0);
        acc[m][n] = __builtin_amdgcn_mfma_f32_16x16x32_bf16(av[m], bh[n], acc[m][n], 0, 0, 0);
      }
    __syncthreads();
  }
#pragma unroll
  for (int m = 0; m < 4; ++m) {
    int gr0 = m0 + wr * 64 + m * 16 + fq * 4;
#pragma unroll
    for (int n = 0; n < 4; ++n) {
      int gc = n0 + wc * 64 + n * 16 + fr;
      _Float16* cp = C + (size_t)gr0 * 512 + gc;
#pragma unroll
      for (int r = 0; r < 4; ++r) cp[(size_t)r * 512] = (_Float16)acc[m][n][r];
    }
  }
}

// ---------------------------------------------------------------------------
// masked-position scores (step-invariant), list-based fixup (round-7 exact).
// ---------------------------------------------------------------------------
__global__ __launch_bounds__(1024) void k_mscore(
    const int* __restrict__ slens, const float* __restrict__ vvec,
    const _Float16* __restrict__ Vc16, float* __restrict__ scores,
    int* __restrict__ fixcnt, int* __restrict__ fixlist) {
  int nb = blockIdx.x & 63, cb = blockIdx.x >> 6;
  int t = threadIdx.x;
  int len = slens[nb];
  int w = t >> 6, lane = t & 63;
  int hb = lane << 3;
  float4 v0 = *(const float4*)(vvec + hb);
  float4 v1 = *(const float4*)(vvec + hb + 4);
  float vv[8] = {v0.x, v0.y, v0.z, v0.w, v1.x, v1.y, v1.z, v1.w};
  int s0 = max(cb * 128, len + 1);
  int s_end = min((cb + 1) * 128, W_);
  for (int s = s0 + w; s < s_end; s += 16) {
    h16x8 x8 = *(const h16x8*)(Vc16 + ((size_t)nb * W_ + s) * H_ + hb);
    float acc = 0.0f;
#pragma unroll
    for (int i = 0; i < 8; ++i) {
      float vcv = (float)x8[i];
      if (fabsf(vcv) < 6e-5f) {
        int idx = atomicAdd(fixcnt, 1);
        if (idx < FIXCAP_) fixlist[idx] = (nb << 20) | (s << 10) | (hb + i);
      } else {
        acc += (vcv > 0.0f) ? -vv[i] : vv[i];
      }
    }
    acc = wred_sum(acc);
    if (lane == 0) scores[nb * S_ + s] = acc;
  }
}

// ---------------------------------------------------------------------------
// fixup: one wave per uncertain element; coalesced fp64 dot, atomic score add.
// ---------------------------------------------------------------------------
__global__ __launch_bounds__(256) void k_fix(
    const float* __restrict__ ctx, const float* __restrict__ Vw,
    const float* __restrict__ vvec, const int* __restrict__ fixcnt,
    const int* __restrict__ fixlist, float* __restrict__ scores) {
  int wid = (blockIdx.x * 256 + threadIdx.x) >> 6;
  int lane = threadIdx.x & 63;
  int cnt = min(*fixcnt, FIXCAP_);
  for (int e = wid; e < cnt; e += 1024) {
    int pk = fixlist[e];
    int n = pk >> 20, s = (pk >> 10) & 1023, h = pk & 1023;
    const float* cr = ctx + ((size_t)n * W_ + s) * TWOH_ + lane * 16;
    const float* wr = Vw + (size_t)h * TWOH_ + lane * 16;
    double acc = 0.0;
#pragma unroll
    for (int i = 0; i < 16; ++i) acc += (double)cr[i] * (double)wr[i];
#pragma unroll
    for (int m = 32; m > 0; m >>= 1) acc += __shfl_xor(acc, m, 64);
    if (lane == 0) {
      float vh = vvec[h];
      float contrib = (acc > 0.0) ? -vh : ((acc < 0.0) ? vh : 0.0f);
      if (contrib != 0.0f) atomicAdd(&scores[n * S_ + s], contrib);
    }
  }
}

// ---------------------------------------------------------------------------
// prep2: Cmask[n][d] = sum_masked exp(ms) * (-1e10*ctx)  (fp32 ctx!)
// ---------------------------------------------------------------------------
__global__ __launch_bounds__(1024) void k_prep2(
    const float* __restrict__ ctx, const int* __restrict__ slens,
    const float* __restrict__ scores, float* __restrict__ Cmask) {
  __shared__ float4 red4[16 * 64];
  int nb = blockIdx.x & 63, cb = blockIdx.x >> 6;
  int t = threadIdx.x;
  int len = slens[nb];
  int dl = t & 63, sl = t >> 6;
  int d4 = cb * 256 + dl * 4;
  const float4* cp = (const float4*)(ctx + (size_t)nb * W_ * TWOH_) + (d4 >> 2);
  float4 acc = make_float4(0.f, 0.f, 0.f, 0.f);
#pragma unroll 4
  for (int s = len + 1 + sl; s < W_; s += 16) {
    float ew = __expf(scores[nb * S_ + s]);
    float4 c4 = cp[(size_t)s * (TWOH_ / 4)];
    acc.x += ew * c4.x; acc.y += ew * c4.y;
    acc.z += ew * c4.z; acc.w += ew * c4.w;
  }
  red4[sl * 64 + dl] = acc;
  __syncthreads();
  if (sl == 0) {
    float4 s4 = red4[dl];
#pragma unroll
    for (int i = 1; i < 16; ++i) {
      float4 o = red4[i * 64 + dl];
      s4.x += o.x; s4.y += o.y; s4.z += o.z; s4.w += o.w;
    }
    s4.x *= -1.0e10f; s4.y *= -1.0e10f; s4.z *= -1.0e10f; s4.w *= -1.0e10f;
    *(float4*)(Cmask + nb * TWOH_ + d4) = s4;
  }
}

// ---------------------------------------------------------------------------
// K1: ONE BLOCK PER BATCH ROW n — hW + scores (LDS) + softmax + aligned.
// grid 64 x 1024. Masked scores read from global (step-invariant); valid &
// appended computed here; scores never round-trip through global.
// ---------------------------------------------------------------------------
__global__ __launch_bounds__(1024) void k_step(
    const int* __restrict__ slens, const float* __restrict__ hc,
    const _Float16* __restrict__ W16, const _Float16* __restrict__ Vc16,
    const float* __restrict__ vvec, const float* __restrict__ scores_g,
    const float* __restrict__ Cmask, const unsigned short* __restrict__ ctxb,
    float* __restrict__ alignedb, float* __restrict__ out, int k) {
  __shared__ float s_hW[512];
  __shared__ float s_sc[520];
  __shared__ float beta[520];
  __shared__ float wsum[16];
  __shared__ float redl[8 * 128 * 8];  // [sl][dg][8] = 32 KB
  const int n = blockIdx.x;
  const int t = threadIdx.x;
  const int w = t >> 6, lane = t & 63;
  const int hb = lane << 3;
  const int len = slens[n];
  const int smax = min(len, W_ - 1);

  // ---- A: hW into LDS (wave-per-row, coalesced 1KB fp16 row loads) ----
  if (k == 0) {
    if (t < 512) s_hW[t] = 0.0f;
  } else {
    float4 ha = *(const float4*)(hc + (size_t)n * H_ + hb);
    float4 hbv = *(const float4*)(hc + (size_t)n * H_ + hb + 4);
    float hx[8] = {ha.x, ha.y, ha.z, ha.w, hbv.x, hbv.y, hbv.z, hbv.w};
    for (int o = w; o < 512; o += 16) {
      h16x8 w8 = *(const h16x8*)(W16 + (size_t)o * H_ + hb);
      float a = 0.0f;
#pragma unroll
      for (int i = 0; i < 8; ++i) a += hx[i] * (float)w8[i];
      a = wred_sum(a);
      if (lane == 0) s_hW[o] = a;
    }
  }
  // masked scores: coalesced sweep from global (written once by k_mscore/k_fix)
  for (int i = t; i < 512; i += 1024)
    if (i > smax) s_sc[i] = scores_g[n * S_ + i];
  __syncthreads();

  // ---- B: valid-position scores into LDS (wave per position, 4 in flight) --
  float4 h0 = *(const float4*)(s_hW + hb);
  float4 h1 = *(const float4*)(s_hW + hb + 4);
  float4 v0 = *(const float4*)(vvec + hb);
  float4 v1 = *(const float4*)(vvec + hb + 4);
  float hw[8] = {h0.x, h0.y, h0.z, h0.w, h1.x, h1.y, h1.z, h1.w};
  float vv[8] = {v0.x, v0.y, v0.z, v0.w, v1.x, v1.y, v1.z, v1.w};
  const _Float16* vcb = Vc16 + (size_t)n * W_ * H_ + hb;
  int s = w;
  for (; s + 48 <= smax; s += 64) {
    h16x8 x0 = *(const h16x8*)(vcb + (size_t)s * H_);
    h16x8 x1 = *(const h16x8*)(vcb + (size_t)(s + 16) * H_);
    h16x8 x2 = *(const h16x8*)(vcb + (size_t)(s + 32) * H_);
    h16x8 x3 = *(const h16x8*)(vcb + (size_t)(s + 48) * H_);
    float a0 = 0.f, a1 = 0.f, a2 = 0.f, a3 = 0.f;
#pragma unroll
    for (int i = 0; i < 8; ++i) {
      a0 += tanh_fast((float)x0[i] + hw[i]) * vv[i];
      a1 += tanh_fast((float)x1[i] + hw[i]) * vv[i];
      a2 += tanh_fast((float)x2[i] + hw[i]) * vv[i];
      a3 += tanh_fast((float)x3[i] + hw[i]) * vv[i];
    }
    a0 = wred_sum(a0); a1 = wred_sum(a1);
    a2 = wred_sum(a2); a3 = wred_sum(a3);
    if (lane == 0) {
      s_sc[s] = a0; s_sc[s + 16] = a1;
      s_sc[s + 32] = a2; s_sc[s + 48] = a3;
    }
  }
  for (; s <= smax; s += 16) {
    h16x8 x8 = *(const h16x8*)(vcb + (size_t)s * H_);
    float acc = 0.0f;
#pragma unroll
    for (int i = 0; i < 8; ++i) acc += tanh_fast((float)x8[i] + hw[i]) * vv[i];
    acc = wred_sum(acc);
    if (lane == 0) s_sc[s] = acc;
  }
  if (w == 15) {  // appended zero row
    float acc = 0.0f;
#pragma unroll
    for (int i = 0; i < 8; ++i) acc += tanh_fast(hw[i]) * vv[i];
    acc = wred_sum(acc);
    if (lane == 0) s_sc[W_] = acc;
  }
  __syncthreads();

  // ---- C: softmax (no max pass) + beta + out ----
  float e = (t < S_) ? __expf(s_sc[t]) : 0.0f;
  float ws_ = wred_sum(e);
  if (lane == 0) wsum[w] = ws_;
  __syncthreads();
  float D = 0.0f;
#pragma unroll
  for (int i = 0; i < 16; ++i) D += wsum[i];
  if (t < S_) {
    float bt = e / D;
    beta[t] = bt;
    out[(size_t)(n * KS_ + k) * S_ + t] = bt;
  }
  __syncthreads();

  // ---- D: aligned (bf16 ctx), 128 d-groups x 8 s-slices ----
  int dg = t & 127, sl = t >> 7;
  int d8 = dg * 8;
  const unsigned short* cp = ctxb + (size_t)n * W_ * TWOH_ + d8;
  float a[8] = {};
  s = sl;
  for (; s + 8 <= smax; s += 16) {  // 2 rows in flight
    float b0 = beta[s], b1 = beta[s + 8];
    s16x8 c0 = *(const s16x8*)(cp + (size_t)s * TWOH_);
    s16x8 c1 = *(const s16x8*)(cp + (size_t)(s + 8) * TWOH_);
#pragma unroll
    for (int i = 0; i < 8; ++i)
      a[i] += b0 * bf2f((unsigned short)c0[i]) + b1 * bf2f((unsigned short)c1[i]);
  }
  for (; s <= smax; s += 8) {
    float bt = beta[s];
    s16x8 c = *(const s16x8*)(cp + (size_t)s * TWOH_);
#pragma unroll
    for (int i = 0; i < 8; ++i) a[i] += bt * bf2f((unsigned short)c[i]);
  }
  float4* rp = (float4*)(redl + sl * 1024 + d8);
  rp[0] = make_float4(a[0], a[1], a[2], a[3]);
  rp[1] = make_float4(a[4], a[5], a[6], a[7]);
  __syncthreads();
  {  // E: final reduce — each thread owns one d
    float ssum = 0.0f;
#pragma unroll
    for (int q = 0; q < 8; ++q) ssum += redl[q * 1024 + t];
    float coef = 1.0f / D;
    alignedb[n * TWOH_ + t] = ssum + coef * Cmask[n * TWOH_ + t];
  }
}

// ---------------------------------------------------------------------------
// K2: GRU cell.  grid 256 x 1024; block owns j0=2b,2b+1; LDS-staged weights.
// ---------------------------------------------------------------------------
__global__ __launch_bounds__(1024) void k_gru(
    const float* __restrict__ alignedb, const float* __restrict__ hc,
    const float* __restrict__ wih, const float* __restrict__ whh,
    const float* __restrict__ bih, const float* __restrict__ bhh,
    float* __restrict__ hnx) {
  __shared__ float ls_wih[6 * TWOH_];
  __shared__ float ls_whh[6 * H_];
  __shared__ float part[8 * 128 * 6];
  int b = blockIdx.x;
  int t = threadIdx.x;
  const int j0 = 2 * b;
  for (int i = t; i < 6 * TWOH_; i += 1024) {
    int row = i >> 10, d = i & 1023;
    int jl = row / 3, g = row - jl * 3;
    ls_wih[i] = wih[(size_t)(g * H_ + j0 + jl) * TWOH_ + d];
  }
  for (int i = t; i < 6 * H_; i += 1024) {
    int row = i >> 9, d = i & 511;
    int jl = row / 3, g = row - jl * 3;
    ls_whh[i] = whh[(size_t)(g * H_ + j0 + jl) * H_ + d];
  }
  __syncthreads();
  int nj = t & 127, sl = t >> 7;
  int n = nj & 63, jl = nj >> 6;
  const float* ar = alignedb + n * TWOH_ + sl * 128;
  const float* hr = hc + n * H_ + sl * 64;
  const float* w0 = ls_wih + (jl * 3 + 0) * TWOH_ + sl * 128;
  const float* w1 = ls_wih + (jl * 3 + 1) * TWOH_ + sl * 128;
  const float* w2 = ls_wih + (jl * 3 + 2) * TWOH_ + sl * 128;
  const float* u0 = ls_whh + (jl * 3 + 0) * H_ + sl * 64;
  const float* u1 = ls_whh + (jl * 3 + 1) * H_ + sl * 64;
  const float* u2 = ls_whh + (jl * 3 + 2) * H_ + sl * 64;
  float g0 = 0.f, g1 = 0.f, g2 = 0.f;
#pragma unroll 8
  for (int i = 0; i < 128; i += 4) {
    float4 a4 = *(const float4*)(ar + i);
    g0 += a4.x * w0[i] + a4.y * w0[i + 1] + a4.z * w0[i + 2] + a4.w * w0[i + 3];
    g1 += a4.x * w1[i] + a4.y * w1[i + 1] + a4.z * w1[i + 2] + a4.w * w1[i + 3];
    g2 += a4.x * w2[i] + a4.y * w2[i + 1] + a4.z * w2[i + 2] + a4.w * w2[i + 3];
  }
  float q0 = 0.f, q1 = 0.f, q2 = 0.f;
#pragma unroll 8
  for (int i = 0; i < 64; i += 4) {
    float4 h4 = *(const float4*)(hr + i);
    q0 += h4.x * u0[i] + h4.y * u0[i + 1] + h4.z * u0[i + 2] + h4.w * u0[i + 3];
    q1 += h4.x * u1[i] + h4.y * u1[i + 1] + h4.z * u1[i + 2] + h4.w * u1[i + 3];
    q2 += h4.x * u2[i] + h4.y * u2[i + 1] + h4.z * u2[i + 2] + h4.w * u2[i + 3];
  }
  float* pp = part + (sl * 128 + nj) * 6;
  pp[0] = g0; pp[1] = g1; pp[2] = g2; pp[3] = q0; pp[4] = q1; pp[5] = q2;
  __syncthreads();
  if (t < 128) {
    int n2 = t & 63, jl2 = t >> 6;
    int j = j0 + jl2;
    float G0 = 0.f, G1 = 0.f, G2 = 0.f, Q0 = 0.f, Q1 = 0.f, Q2 = 0.f;
#pragma unroll
    for (int s = 0; s < 8; ++s) {
      float* p = part + (s * 128 + t) * 6;
      G0 += p[0]; G1 += p[1]; G2 += p[2];
      Q0 += p[3]; Q1 += p[4]; Q2 += p[5];
    }
    float r = sigmoid_f(G0 + bih[j] + Q0 + bhh[j]);
    float z = sigmoid_f(G1 + bih[H_ + j] + Q1 + bhh[H_ + j]);
    float nc = tanh_fast(G2 + bih[2 * H_ + j] + r * (Q2 + bhh[2 * H_ + j]));
    hnx[n2 * H_ + j] = (1.0f - z) * nc + z * hc[n2 * H_ + j];
  }
}

extern "C" void kernel_launch(void* const* d_in, const int* in_sizes, int n_in,
                              void* d_out, int out_size, void* d_ws, size_t ws_size,
                              hipStream_t stream) {
  const float* ctx = (const float*)d_in[0];
  const int* slens = (const int*)d_in[1];
  const float* Vw = (const float*)d_in[3];
  const float* Ww = (const float*)d_in[4];
  const float* vvec = (const float*)d_in[5];
  const float* wih = (const float*)d_in[6];
  const float* whh = (const float*)d_in[7];
  const float* bih = (const float*)d_in[8];
  const float* bhh = (const float*)d_in[9];
  float* out = (float*)d_out;

  char* p = (char*)d_ws;
  _Float16* Vc16 = (_Float16*)p;      p += (size_t)N_ * W_ * H_ * 2;   // 33.5 MB
  float* scores = (float*)p;          p += (size_t)N_ * S_ * 4;
  int* fixcnt = (int*)p;              p += 256;
  int* fixlist = (int*)p;             p += (size_t)FIXCAP_ * 4;
  float* Cm = (float*)p;              p += (size_t)N_ * TWOH_ * 4;
  float* hb = (float*)p;              p += (size_t)2 * N_ * H_ * 4;
  float* al = (float*)p;              p += (size_t)N_ * TWOH_ * 4;
  unsigned short* Ahi = (unsigned short*)p;  p += (size_t)32768 * 1024 * 2;
  unsigned short* Alo = (unsigned short*)p;  p += (size_t)32768 * 1024 * 2;
  unsigned short* Bhi = (unsigned short*)p;  p += (size_t)512 * 1024 * 2;
  unsigned short* Blo = (unsigned short*)p;  p += (size_t)512 * 1024 * 2;
  _Float16* W16 = (_Float16*)p;       p += (size_t)512 * 512 * 2;
  size_t need = (size_t)(p - (char*)d_ws);
  if (ws_size < need) return;  // proven ws >= ~205 MB (r4); need ~173 MB

  hipMemsetAsync(hb, 0, (size_t)N_ * H_ * sizeof(float), stream);
  hipMemsetAsync(fixcnt, 0, sizeof(int), stream);
  k_cvt2<<<2048, 256, 0, stream>>>((const float4*)ctx, Ahi, Alo,
                                   (const float4*)Vw, Bhi, Blo,
                                   (const float4*)Ww, W16);
  mfma_gemm<<<1024, 256, 0, stream>>>(Ahi, Alo, Bhi, Blo, Vc16);
  k_mscore<<<256, 1024, 0, stream>>>(slens, vvec, Vc16, scores, fixcnt, fixlist);
  k_fix<<<256, 256, 0, stream>>>(ctx, Vw, vvec, fixcnt, fixlist, scores);
  k_prep2<<<256, 1024, 0, stream>>>(ctx, slens, scores, Cm);

  for (int k = 0; k < KS_; ++k) {
    const float* hc = hb + (k & 1) * (N_ * H_);
    float* hn = hb + ((k + 1) & 1) * (N_ * H_);
    k_step<<<64, 1024, 0, stream>>>(slens, hc, W16, Vc16, vvec, scores, Cm,
                                    Ahi, al, out, k);
    k_gru<<<256, 1024, 0, stream>>>(al, hc, wih, whh, bih, bhh, hn);
  }
}

// Round 13
// 638.003 us; speedup vs baseline: 1.5356x; 1.5356x over previous
//
#include <hip/hip_runtime.h>

#define N_    64
#define W_    512
#define H_    512
#define S_    513
#define TWOH_ 1024
#define KS_   8
#define FIXCAP_ 131072

typedef short s16x8 __attribute__((ext_vector_type(8)));
typedef float f32x4 __attribute__((ext_vector_type(4)));
typedef _Float16 h16x8 __attribute__((ext_vector_type(8)));

__device__ __forceinline__ float tanh_fast(float x) {
  float xc = fminf(fmaxf(x, -15.0f), 15.0f);
  float e = __expf(2.0f * xc);
  return (e - 1.0f) / (e + 1.0f);
}
__device__ __forceinline__ float sigmoid_f(float x) {
  return 1.0f / (1.0f + __expf(-x));
}
__device__ __forceinline__ float wred_sum(float v) {
#pragma unroll
  for (int m = 32; m > 0; m >>= 1) v += __shfl_xor(v, m, 64);
  return v;
}
__device__ __forceinline__ float bf2f(unsigned short u) {
  return __uint_as_float(((unsigned)u) << 16);
}

__device__ __forceinline__ void gld_lds16(const void* g, void* s) {
  __builtin_amdgcn_global_load_lds((__attribute__((address_space(1))) void*)g,
                                   (__attribute__((address_space(3))) void*)s,
                                   16, 0, 0);
}

// ---------------------------------------------------------------------------
// conversions in one dispatch: ctx/Vw -> split-bf16 (hi,lo).
// ---------------------------------------------------------------------------
__global__ __launch_bounds__(256) void k_cvt2(
    const float4* __restrict__ xa, unsigned short* __restrict__ Ahi,
    unsigned short* __restrict__ Alo, const float4* __restrict__ xb,
    unsigned short* __restrict__ Bhi, unsigned short* __restrict__ Blo) {
  const int NA = 8388608;          // ctx float4 count
  const int NT = NA + 131072;      // + Vw float4 count
  for (int i = blockIdx.x * 256 + threadIdx.x; i < NT; i += gridDim.x * 256) {
    bool isA = (i < NA);
    float4 v = isA ? xa[i] : xb[i - NA];
    float vs[4] = {v.x, v.y, v.z, v.w};
    unsigned short hb[4], lb[4];
#pragma unroll
    for (int j = 0; j < 4; ++j) {
      unsigned u = __float_as_uint(vs[j]);
      unsigned short h = (unsigned short)((u + 0x7FFFu + ((u >> 16) & 1u)) >> 16);
      float hf = __uint_as_float((unsigned)h << 16);
      float lf = vs[j] - hf;
      unsigned u2 = __float_as_uint(lf);
      unsigned short l = (unsigned short)((u2 + 0x7FFFu + ((u2 >> 16) & 1u)) >> 16);
      hb[j] = h; lb[j] = l;
    }
    ushort4 h4; h4.x = hb[0]; h4.y = hb[1]; h4.z = hb[2]; h4.w = hb[3];
    ushort4 l4; l4.x = lb[0]; l4.y = lb[1]; l4.z = lb[2]; l4.w = lb[3];
    if (isA) {
      ((ushort4*)Ahi)[i] = h4;
      ((ushort4*)Alo)[i] = l4;
    } else {
      ((ushort4*)Bhi)[i - NA] = h4;
      ((ushort4*)Blo)[i - NA] = l4;
    }
  }
}

// ---------------------------------------------------------------------------
// Vc16 = (half)(A * B^T) via 3-product split-bf16 MFMA (round-7 exact).
// ---------------------------------------------------------------------------
__global__ __launch_bounds__(256, 2) void mfma_gemm(
    const unsigned short* __restrict__ Ahi, const unsigned short* __restrict__ Alo,
    const unsigned short* __restrict__ Bhi, const unsigned short* __restrict__ Blo,
    _Float16* __restrict__ C) {
  __shared__ unsigned short sAh[4096], sAl[4096], sBh[4096], sBl[4096];
  int bid = blockIdx.x;
  int swz = (bid & 7) * 128 + (bid >> 3);  // 1024 wgs, bijective, XCD-chunked
  int mt = swz >> 2, nt = swz & 3;
  int m0 = mt * 128, n0 = nt * 128;
  int tid = threadIdx.x;
  int wave = tid >> 6, lane = tid & 63;
  int wr = wave >> 1, wc = wave & 1;
  int fr = lane & 15, fq = lane >> 4;
  int rA = tid >> 2;
  int cA = (tid & 3) * 8;

  f32x4 acc[4][4] = {};

  const size_t a_row0 = (size_t)(m0 + rA) << 10;
  const size_t a_row1 = (size_t)(m0 + rA + 64) << 10;
  const size_t b_row0 = (size_t)(n0 + rA) << 10;
  const size_t b_row1 = (size_t)(n0 + rA + 64) << 10;
  const int wofs = wave << 9;

  for (int k0 = 0; k0 < 1024; k0 += 32) {
    int off = k0 + cA;
    gld_lds16(Ahi + a_row0 + off, sAh + wofs);
    gld_lds16(Ahi + a_row1 + off, sAh + 2048 + wofs);
    gld_lds16(Alo + a_row0 + off, sAl + wofs);
    gld_lds16(Alo + a_row1 + off, sAl + 2048 + wofs);
    gld_lds16(Bhi + b_row0 + off, sBh + wofs);
    gld_lds16(Bhi + b_row1 + off, sBh + 2048 + wofs);
    gld_lds16(Blo + b_row0 + off, sBl + wofs);
    gld_lds16(Blo + b_row1 + off, sBl + 2048 + wofs);
    __syncthreads();
    s16x8 ah[4], av[4], bh[4], bv[4];
#pragma unroll
    for (int m = 0; m < 4; ++m) {
      int ar = (wr * 64 + m * 16 + fr) * 32 + fq * 8;
      ah[m] = *(const s16x8*)(sAh + ar);
      av[m] = *(const s16x8*)(sAl + ar);
    }
#pragma unroll
    for (int n = 0; n < 4; ++n) {
      int br = (wc * 64 + n * 16 + fr) * 32 + fq * 8;
      bh[n] = *(const s16x8*)(sBh + br);
      bv[n] = *(const s16x8*)(sBl + br);
    }
#pragma unroll
    for (int m = 0; m < 4; ++m)
#pragma unroll
      for (int n = 0; n < 4; ++n) {
        acc[m][n] = __builtin_amdgcn_mfma_f32_16x16x32_bf16(ah[m], bh[n], acc[m][n], 0, 0, 0);
        acc[m][n] = __builtin_amdgcn_mfma_f32_16x16x32_bf16(ah[m], bv[n], acc[m][n], 0, 0, 0);
        acc[m][n] = __builtin_amdgcn_mfma_f32_16x16x32_bf16(av[m], bh[n], acc[m][n], 0, 0, 0);
      }
    __syncthreads();
  }
#pragma unroll
  for (int m = 0; m < 4; ++m) {
    int gr0 = m0 + wr * 64 + m * 16 + fq * 4;
#pragma unroll
    for (int n = 0; n < 4; ++n) {
      int gc = n0 + wc * 64 + n * 16 + fr;
      _Float16* cp = C + (size_t)gr0 * 512 + gc;
#pragma unroll
      for (int r = 0; r < 4; ++r) cp[(size_t)r * 512] = (_Float16)acc[m][n][r];
    }
  }
}

// ---------------------------------------------------------------------------
// masked-position scores (step-invariant), list-based fixup.
// ---------------------------------------------------------------------------
__global__ __launch_bounds__(1024) void k_mscore(
    const int* __restrict__ slens, const float* __restrict__ vvec,
    const _Float16* __restrict__ Vc16, float* __restrict__ scores,
    int* __restrict__ fixcnt, int* __restrict__ fixlist) {
  int nb = blockIdx.x & 63, cb = blockIdx.x >> 6;
  int t = threadIdx.x;
  int len = slens[nb];
  int w = t >> 6, lane = t & 63;
  int hb = lane << 3;
  float4 v0 = *(const float4*)(vvec + hb);
  float4 v1 = *(const float4*)(vvec + hb + 4);
  float vv[8] = {v0.x, v0.y, v0.z, v0.w, v1.x, v1.y, v1.z, v1.w};
  int s0 = max(cb * 128, len + 1);
  int s_end = min((cb + 1) * 128, W_);
  for (int s = s0 + w; s < s_end; s += 16) {
    h16x8 x8 = *(const h16x8*)(Vc16 + ((size_t)nb * W_ + s) * H_ + hb);
    float acc = 0.0f;
#pragma unroll
    for (int i = 0; i < 8; ++i) {
      float vcv = (float)x8[i];
      if (fabsf(vcv) < 6e-5f) {
        int idx = atomicAdd(fixcnt, 1);
        if (idx < FIXCAP_) fixlist[idx] = (nb << 20) | (s << 10) | (hb + i);
      } else {
        acc += (vcv > 0.0f) ? -vv[i] : vv[i];
      }
    }
    acc = wred_sum(acc);
    if (lane == 0) scores[nb * S_ + s] = acc;
  }
}

// ---------------------------------------------------------------------------
// fixup: one wave per uncertain element; coalesced fp64 dot, atomic score add.
// ---------------------------------------------------------------------------
__global__ __launch_bounds__(256) void k_fix(
    const float* __restrict__ ctx, const float* __restrict__ Vw,
    const float* __restrict__ vvec, const int* __restrict__ fixcnt,
    const int* __restrict__ fixlist, float* __restrict__ scores) {
  int wid = (blockIdx.x * 256 + threadIdx.x) >> 6;
  int lane = threadIdx.x & 63;
  int cnt = min(*fixcnt, FIXCAP_);
  for (int e = wid; e < cnt; e += 1024) {
    int pk = fixlist[e];
    int n = pk >> 20, s = (pk >> 10) & 1023, h = pk & 1023;
    const float* cr = ctx + ((size_t)n * W_ + s) * TWOH_ + lane * 16;
    const float* wr = Vw + (size_t)h * TWOH_ + lane * 16;
    double acc = 0.0;
#pragma unroll
    for (int i = 0; i < 16; ++i) acc += (double)cr[i] * (double)wr[i];
#pragma unroll
    for (int m = 32; m > 0; m >>= 1) acc += __shfl_xor(acc, m, 64);
    if (lane == 0) {
      float vh = vvec[h];
      float contrib = (acc > 0.0) ? -vh : ((acc < 0.0) ? vh : 0.0f);
      if (contrib != 0.0f) atomicAdd(&scores[n * S_ + s], contrib);
    }
  }
}

// ---------------------------------------------------------------------------
// prep2: Cmask[n][d] = sum_masked exp(ms) * (-1e10*ctx)  (fp32 ctx!)
// ---------------------------------------------------------------------------
__global__ __launch_bounds__(1024) void k_prep2(
    const float* __restrict__ ctx, const int* __restrict__ slens,
    const float* __restrict__ scores, float* __restrict__ Cmask) {
  __shared__ float4 red4[16 * 64];
  int nb = blockIdx.x & 63, cb = blockIdx.x >> 6;
  int t = threadIdx.x;
  int len = slens[nb];
  int dl = t & 63, sl = t >> 6;
  int d4 = cb * 256 + dl * 4;
  const float4* cp = (const float4*)(ctx + (size_t)nb * W_ * TWOH_) + (d4 >> 2);
  float4 acc = make_float4(0.f, 0.f, 0.f, 0.f);
#pragma unroll 4
  for (int s = len + 1 + sl; s < W_; s += 16) {
    float ew = __expf(scores[nb * S_ + s]);
    float4 c4 = cp[(size_t)s * (TWOH_ / 4)];
    acc.x += ew * c4.x; acc.y += ew * c4.y;
    acc.z += ew * c4.z; acc.w += ew * c4.w;
  }
  red4[sl * 64 + dl] = acc;
  __syncthreads();
  if (sl == 0) {
    float4 s4 = red4[dl];
#pragma unroll
    for (int i = 1; i < 16; ++i) {
      float4 o = red4[i * 64 + dl];
      s4.x += o.x; s4.y += o.y; s4.z += o.z; s4.w += o.w;
    }
    s4.x *= -1.0e10f; s4.y *= -1.0e10f; s4.z *= -1.0e10f; s4.w *= -1.0e10f;
    *(float4*)(Cmask + nb * TWOH_ + d4) = s4;
  }
}

// ---------------------------------------------------------------------------
// hW[n,h] = dot(h[n,:], Ww[h,:]).  grid 128 x 1024; 4 h rows per block.
// (round-8 exact; skipped at k=0 — hWb pre-zeroed)
// ---------------------------------------------------------------------------
__global__ __launch_bounds__(1024) void k_hw(const float* __restrict__ hc,
                                             const float* __restrict__ Ww,
                                             float* __restrict__ hWb) {
  __shared__ float ww[4][512];
  int b = blockIdx.x;
  int t = threadIdx.x;
  int h0 = b * 4;
  for (int i = t; i < 4 * 512; i += 1024)
    ww[i >> 9][i & 511] = Ww[(size_t)(h0 + (i >> 9)) * H_ + (i & 511)];
  __syncthreads();
  int lane = t & 63;
  int hl = (t >> 6) & 3;
  int nh = t >> 8;  // 0..3 -> 16 n each
  const float* wr = &ww[hl][lane << 3];
  float4 w0 = *(const float4*)wr;
  float4 w1 = *(const float4*)(wr + 4);
  for (int n = nh * 16; n < nh * 16 + 16; n += 2) {
    const float* hr0 = hc + (size_t)n * H_ + (lane << 3);
    const float* hr1 = hr0 + H_;
    float4 a0 = *(const float4*)hr0;
    float4 a1 = *(const float4*)(hr0 + 4);
    float4 b0 = *(const float4*)hr1;
    float4 b1 = *(const float4*)(hr1 + 4);
    float acc0 = a0.x * w0.x + a0.y * w0.y + a0.z * w0.z + a0.w * w0.w +
                 a1.x * w1.x + a1.y * w1.y + a1.z * w1.z + a1.w * w1.w;
    float acc1 = b0.x * w0.x + b0.y * w0.y + b0.z * w0.z + b0.w * w0.w +
                 b1.x * w1.x + b1.y * w1.y + b1.z * w1.z + b1.w * w1.w;
    acc0 = wred_sum(acc0);
    acc1 = wred_sum(acc1);
    if (lane == 0) {
      hWb[(size_t)n * H_ + h0 + hl] = acc0;
      hWb[(size_t)(n + 1) * H_ + h0 + hl] = acc1;
    }
  }
}

// ---------------------------------------------------------------------------
// K1: valid-position scores.  grid 512 (nb, cb=64-s chunk) x 1024. (r8 exact)
// ---------------------------------------------------------------------------
__global__ __launch_bounds__(1024) void k_scores(
    const int* __restrict__ slens, const float* __restrict__ hWb,
    const _Float16* __restrict__ Vc16, const float* __restrict__ vvec,
    float* __restrict__ scores) {
  int nb = blockIdx.x & 63, cb = blockIdx.x >> 6;  // cb 0..7
  int t = threadIdx.x;
  int len = slens[nb];
  int smax = min(len, W_ - 1);
  int w = t >> 6, lane = t & 63;
  int hb = lane << 3;
  float4 h0 = *(const float4*)(hWb + nb * H_ + hb);
  float4 h1 = *(const float4*)(hWb + nb * H_ + hb + 4);
  float4 v0 = *(const float4*)(vvec + hb);
  float4 v1 = *(const float4*)(vvec + hb + 4);
  float hw[8] = {h0.x, h0.y, h0.z, h0.w, h1.x, h1.y, h1.z, h1.w};
  float vv[8] = {v0.x, v0.y, v0.z, v0.w, v1.x, v1.y, v1.z, v1.w};
  int s_end = min((cb + 1) * 64 - 1, smax);
  const _Float16* vcb = Vc16 + (size_t)nb * W_ * H_ + hb;
  int s = cb * 64 + w;
  for (; s + 16 <= s_end; s += 32) {  // 2 positions in flight
    h16x8 x0 = *(const h16x8*)(vcb + (size_t)s * H_);
    h16x8 x1 = *(const h16x8*)(vcb + (size_t)(s + 16) * H_);
    float a0 = 0.f, a1 = 0.f;
#pragma unroll
    for (int i = 0; i < 8; ++i) {
      a0 += tanh_fast((float)x0[i] + hw[i]) * vv[i];
      a1 += tanh_fast((float)x1[i] + hw[i]) * vv[i];
    }
    a0 = wred_sum(a0); a1 = wred_sum(a1);
    if (lane == 0) {
      scores[nb * S_ + s] = a0;
      scores[nb * S_ + s + 16] = a1;
    }
  }
  for (; s <= s_end; s += 16) {
    h16x8 x8 = *(const h16x8*)(vcb + (size_t)s * H_);
    float acc = 0.0f;
#pragma unroll
    for (int i = 0; i < 8; ++i) acc += tanh_fast((float)x8[i] + hw[i]) * vv[i];
    acc = wred_sum(acc);
    if (lane == 0) scores[nb * S_ + s] = acc;
  }
  if (cb == 7 && w == 15) {  // appended zero row
    float acc = 0.0f;
#pragma unroll
    for (int i = 0; i < 8; ++i) acc += tanh_fast(hw[i]) * vv[i];
    acc = wred_sum(acc);
    if (lane == 0) scores[nb * S_ + W_] = acc;
  }
}

// ---------------------------------------------------------------------------
// K2: softmax (no max pass) + beta out + aligned (bf16 ctx = Ahi) + Cmask.
// grid 512 (nb, cb=128-d chunk) x 1024.  (round-8 exact)
// ---------------------------------------------------------------------------
__global__ __launch_bounds__(1024) void k_soft_aligned(
    const unsigned short* __restrict__ ctxb, const int* __restrict__ slens,
    const float* __restrict__ scores, const float* __restrict__ Cmask,
    float* __restrict__ alignedb, float* __restrict__ out, int k) {
  __shared__ float beta[520];
  __shared__ float wsum[16];
  __shared__ float redl[64 * 16 * 8];  // [sl][dl][8] = 32 KB
  int nb = blockIdx.x & 63, cb = blockIdx.x >> 6;  // cb 0..7
  int t = threadIdx.x;
  int len = slens[nb];
  int smax = min(len, W_ - 1);

  float e = (t < S_) ? __expf(scores[nb * S_ + t]) : 0.0f;
  float ws_ = wred_sum(e);
  if ((t & 63) == 0) wsum[t >> 6] = ws_;
  __syncthreads();
  float D = 0.0f;
#pragma unroll
  for (int i = 0; i < 16; ++i) D += wsum[i];
  if (t < S_) {
    float bt = e / D;
    beta[t] = bt;
    if (cb == 0) out[(size_t)(nb * KS_ + k) * S_ + t] = bt;
  }
  __syncthreads();

  int dl = t & 15, sl = t >> 4;  // 16 d-groups x 64 s-slices
  int d8 = cb * 128 + dl * 8;
  const unsigned short* cp = ctxb + (size_t)nb * W_ * TWOH_ + d8;
  float a[8] = {};
  int s = sl;
  for (; s + 64 <= smax; s += 128) {  // 2 rows in flight
    float b0 = beta[s], b1 = beta[s + 64];
    s16x8 c0 = *(const s16x8*)(cp + (size_t)s * TWOH_);
    s16x8 c1 = *(const s16x8*)(cp + (size_t)(s + 64) * TWOH_);
#pragma unroll
    for (int i = 0; i < 8; ++i)
      a[i] += b0 * bf2f((unsigned short)c0[i]) + b1 * bf2f((unsigned short)c1[i]);
  }
  for (; s <= smax; s += 64) {
    float bt = beta[s];
    s16x8 c = *(const s16x8*)(cp + (size_t)s * TWOH_);
#pragma unroll
    for (int i = 0; i < 8; ++i) a[i] += bt * bf2f((unsigned short)c[i]);
  }
  float4* rp = (float4*)(redl + sl * 128 + dl * 8);
  rp[0] = make_float4(a[0], a[1], a[2], a[3]);
  rp[1] = make_float4(a[4], a[5], a[6], a[7]);
  __syncthreads();
  if (t < 128) {  // one thread per output float
    float ssum = 0.0f;
#pragma unroll 16
    for (int q = 0; q < 64; ++q) ssum += redl[q * 128 + t];
    float coef = 1.0f / D;
    int dd = nb * TWOH_ + cb * 128 + t;
    alignedb[dd] = ssum + coef * Cmask[dd];
  }
}

// ---------------------------------------------------------------------------
// K3: GRU cell.  grid 256 x 1024; block owns j0=2b,2b+1; LDS-staged weights.
// (round-8 exact)
// ---------------------------------------------------------------------------
__global__ __launch_bounds__(1024) void k_gru(
    const float* __restrict__ alignedb, const float* __restrict__ hc,
    const float* __restrict__ wih, const float* __restrict__ whh,
    const float* __restrict__ bih, const float* __restrict__ bhh,
    float* __restrict__ hnx) {
  __shared__ float ls_wih[6 * TWOH_];
  __shared__ float ls_whh[6 * H_];
  __shared__ float part[8 * 128 * 6];
  int b = blockIdx.x;
  int t = threadIdx.x;
  const int j0 = 2 * b;
  for (int i = t; i < 6 * TWOH_; i += 1024) {
    int row = i >> 10, d = i & 1023;
    int jl = row / 3, g = row - jl * 3;
    ls_wih[i] = wih[(size_t)(g * H_ + j0 + jl) * TWOH_ + d];
  }
  for (int i = t; i < 6 * H_; i += 1024) {
    int row = i >> 9, d = i & 511;
    int jl = row / 3, g = row - jl * 3;
    ls_whh[i] = whh[(size_t)(g * H_ + j0 + jl) * H_ + d];
  }
  __syncthreads();
  int nj = t & 127, sl = t >> 7;
  int n = nj & 63, jl = nj >> 6;
  const float* ar = alignedb + n * TWOH_ + sl * 128;
  const float* hr = hc + n * H_ + sl * 64;
  const float* w0 = ls_wih + (jl * 3 + 0) * TWOH_ + sl * 128;
  const float* w1 = ls_wih + (jl * 3 + 1) * TWOH_ + sl * 128;
  const float* w2 = ls_wih + (jl * 3 + 2) * TWOH_ + sl * 128;
  const float* u0 = ls_whh + (jl * 3 + 0) * H_ + sl * 64;
  const float* u1 = ls_whh + (jl * 3 + 1) * H_ + sl * 64;
  const float* u2 = ls_whh + (jl * 3 + 2) * H_ + sl * 64;
  float g0 = 0.f, g1 = 0.f, g2 = 0.f;
#pragma unroll 8
  for (int i = 0; i < 128; i += 4) {
    float4 a4 = *(const float4*)(ar + i);
    g0 += a4.x * w0[i] + a4.y * w0[i + 1] + a4.z * w0[i + 2] + a4.w * w0[i + 3];
    g1 += a4.x * w1[i] + a4.y * w1[i + 1] + a4.z * w1[i + 2] + a4.w * w1[i + 3];
    g2 += a4.x * w2[i] + a4.y * w2[i + 1] + a4.z * w2[i + 2] + a4.w * w2[i + 3];
  }
  float q0 = 0.f, q1 = 0.f, q2 = 0.f;
#pragma unroll 8
  for (int i = 0; i < 64; i += 4) {
    float4 h4 = *(const float4*)(hr + i);
    q0 += h4.x * u0[i] + h4.y * u0[i + 1] + h4.z * u0[i + 2] + h4.w * u0[i + 3];
    q1 += h4.x * u1[i] + h4.y * u1[i + 1] + h4.z * u1[i + 2] + h4.w * u1[i + 3];
    q2 += h4.x * u2[i] + h4.y * u2[i + 1] + h4.z * u2[i + 2] + h4.w * u2[i + 3];
  }
  float* pp = part + (sl * 128 + nj) * 6;
  pp[0] = g0; pp[1] = g1; pp[2] = g2; pp[3] = q0; pp[4] = q1; pp[5] = q2;
  __syncthreads();
  if (t < 128) {
    int n2 = t & 63, jl2 = t >> 6;
    int j = j0 + jl2;
    float G0 = 0.f, G1 = 0.f, G2 = 0.f, Q0 = 0.f, Q1 = 0.f, Q2 = 0.f;
#pragma unroll
    for (int s = 0; s < 8; ++s) {
      float* p = part + (s * 128 + t) * 6;
      G0 += p[0]; G1 += p[1]; G2 += p[2];
      Q0 += p[3]; Q1 += p[4]; Q2 += p[5];
    }
    float r = sigmoid_f(G0 + bih[j] + Q0 + bhh[j]);
    float z = sigmoid_f(G1 + bih[H_ + j] + Q1 + bhh[H_ + j]);
    float nc = tanh_fast(G2 + bih[2 * H_ + j] + r * (Q2 + bhh[2 * H_ + j]));
    hnx[n2 * H_ + j] = (1.0f - z) * nc + z * hc[n2 * H_ + j];
  }
}

extern "C" void kernel_launch(void* const* d_in, const int* in_sizes, int n_in,
                              void* d_out, int out_size, void* d_ws, size_t ws_size,
                              hipStream_t stream) {
  const float* ctx = (const float*)d_in[0];
  const int* slens = (const int*)d_in[1];
  const float* Vw = (const float*)d_in[3];
  const float* Ww = (const float*)d_in[4];
  const float* vvec = (const float*)d_in[5];
  const float* wih = (const float*)d_in[6];
  const float* whh = (const float*)d_in[7];
  const float* bih = (const float*)d_in[8];
  const float* bhh = (const float*)d_in[9];
  float* out = (float*)d_out;

  char* p = (char*)d_ws;
  _Float16* Vc16 = (_Float16*)p;      p += (size_t)N_ * W_ * H_ * 2;   // 33.5 MB
  float* scores = (float*)p;          p += (size_t)N_ * S_ * 4;
  int* fixcnt = (int*)p;              p += 256;
  int* fixlist = (int*)p;             p += (size_t)FIXCAP_ * 4;
  float* Cm = (float*)p;              p += (size_t)N_ * TWOH_ * 4;
  float* hb = (float*)p;              p += (size_t)2 * N_ * H_ * 4;
  float* hWb = (float*)p;             p += (size_t)N_ * H_ * 4;
  float* al = (float*)p;              p += (size_t)N_ * TWOH_ * 4;
  unsigned short* Ahi = (unsigned short*)p;  p += (size_t)32768 * 1024 * 2;
  unsigned short* Alo = (unsigned short*)p;  p += (size_t)32768 * 1024 * 2;
  unsigned short* Bhi = (unsigned short*)p;  p += (size_t)512 * 1024 * 2;
  unsigned short* Blo = (unsigned short*)p;  p += (size_t)512 * 1024 * 2;
  size_t need = (size_t)(p - (char*)d_ws);
  if (ws_size < need) return;  // proven ws >= ~205 MB (r4); need ~173 MB

  hipMemsetAsync(hb, 0, (size_t)N_ * H_ * sizeof(float), stream);
  hipMemsetAsync(hWb, 0, (size_t)N_ * H_ * sizeof(float), stream);  // hW(k=0)=0
  hipMemsetAsync(fixcnt, 0, sizeof(int), stream);
  k_cvt2<<<2048, 256, 0, stream>>>((const float4*)ctx, Ahi, Alo,
                                   (const float4*)Vw, Bhi, Blo);
  mfma_gemm<<<1024, 256, 0, stream>>>(Ahi, Alo, Bhi, Blo, Vc16);
  k_mscore<<<256, 1024, 0, stream>>>(slens, vvec, Vc16, scores, fixcnt, fixlist);
  k_fix<<<256, 256, 0, stream>>>(ctx, Vw, vvec, fixcnt, fixlist, scores);
  k_prep2<<<256, 1024, 0, stream>>>(ctx, slens, scores, Cm);

  for (int k = 0; k < KS_; ++k) {
    const float* hc = hb + (k & 1) * (N_ * H_);
    float* hn = hb + ((k + 1) & 1) * (N_ * H_);
    if (k > 0) k_hw<<<128, 1024, 0, stream>>>(hc, Ww, hWb);
    k_scores<<<512, 1024, 0, stream>>>(slens, hWb, Vc16, vvec, scores);
    k_soft_aligned<<<512, 1024, 0, stream>>>(Ahi, slens, scores, Cm, al, out, k);
    k_gru<<<256, 1024, 0, stream>>>(al, hc, wih, whh, bih, bhh, hn);
  }
}